// Round 6
// baseline (186.024 us; speedup 1.0000x reference)
//
#include <hip/hip_runtime.h>
#include <hip/hip_bf16.h>
#include <math.h>

#define B_ 4
#define N_ 512
#define D_ 128
#define O_ 64
#define H_ 4

#define SELU_SCALE 1.0507009873554805f
#define SELU_SCALE_ALPHA 1.7580993408473766f  // scale * alpha

typedef short  short8 __attribute__((ext_vector_type(8)));
typedef float  f32x4  __attribute__((ext_vector_type(4)));

__device__ __forceinline__ ushort bf16rne(float f) {
    uint u = __float_as_uint(f);
    return (ushort)((u + 0x7fffu + ((u >> 16) & 1u)) >> 16);
}
__device__ __forceinline__ void bf16split(float f, ushort& h, ushort& l) {
    h = bf16rne(f);
    float hf = __uint_as_float(((uint)h) << 16);
    l = bf16rne(f - hf);
}

// async global->LDS 16B per lane: dst is wave-uniform base + lane*16
__device__ __forceinline__ void gload_lds16(const void* g, void* l) {
    __builtin_amdgcn_global_load_lds(
        (const __attribute__((address_space(1))) uint*)g,
        (__attribute__((address_space(3))) uint*)l, 16, 0, 0);
}

// ---------------------------------------------------------------------------
// prep_frags (validated r3-r5): four fragment tensors by blockIdx range.
// ---------------------------------------------------------------------------
__global__ __launch_bounds__(256) void prep_frags(
    const float* __restrict__ x, const float* __restrict__ PW,
    const float* __restrict__ NW,
    ushort* __restrict__ xf, ushort* __restrict__ xfT,
    ushort* __restrict__ pwf, ushort* __restrict__ nwf)
{
    const int bid = blockIdx.x;
    const int tid = threadIdx.x;

    if (bid < 128) {
        const int t  = bid * 256 + tid;
        const int jg = t >> 4;
        const int dc = t & 15;
        const int jf = jg >> 4;
        const int kc = dc >> 2, q = dc & 3;
        const int lane = (jg & 15) | (q << 4);

        const f32x4 v0 = *(const f32x4*)&x[t * 8];
        const f32x4 v1 = *(const f32x4*)&x[t * 8 + 4];
        float vv[8] = {v0[0], v0[1], v0[2], v0[3], v1[0], v1[1], v1[2], v1[3]};
        short8 h8, l8;
        #pragma unroll
        for (int e = 0; e < 8; ++e) {
            ushort h, l; bf16split(vv[e], h, l);
            h8[e] = (short)h; l8[e] = (short)l;
        }
        const int fi = (jf * 4 + kc) * 2;
        *(short8*)&xf[(size_t)fi * 512 + lane * 8]       = h8;
        *(short8*)&xf[(size_t)(fi + 1) * 512 + lane * 8] = l8;
    } else if (bid < 256) {
        const int t    = (bid - 128) * 256 + tid;
        const int lane = t & 63, fr = t >> 6;
        const int d0 = fr & 7, kc = (fr >> 3) & 15, b = fr >> 7;
        const int l15 = lane & 15, q4 = lane >> 4;
        short8 h8, l8;
        #pragma unroll
        for (int e = 0; e < 8; ++e) {
            const float v = x[(size_t)((b * 512) + kc * 32 + q4 * 8 + e) * 128 + d0 * 16 + l15];
            ushort h, l; bf16split(v, h, l);
            h8[e] = (short)h; l8[e] = (short)l;
        }
        *(short8*)&xfT[(size_t)(fr * 2) * 512 + lane * 8]     = h8;
        *(short8*)&xfT[(size_t)(fr * 2 + 1) * 512 + lane * 8] = l8;
    } else if (bid < 272) {
        const int t    = (bid - 256) * 256 + tid;
        const int lane = t & 63, fr = t >> 6;
        const int o0 = fr & 3, kc = fr >> 2;
        const int l15 = lane & 15, q4 = lane >> 4;
        short8 h8, l8;
        #pragma unroll
        for (int e = 0; e < 8; ++e) {
            const int kk = kc * 32 + q4 * 8 + e;
            const int d = kk & 127, h = kk >> 7;
            const float v = PW[(d * 4 + h) * O_ + o0 * 16 + l15];
            ushort hh, ll; bf16split(v, hh, ll);
            h8[e] = (short)hh; l8[e] = (short)ll;
        }
        *(short8*)&pwf[(size_t)(fr * 2) * 512 + lane * 8]     = h8;
        *(short8*)&pwf[(size_t)(fr * 2 + 1) * 512 + lane * 8] = l8;
    } else {
        const int t    = (bid - 272) * 256 + tid;
        const int lane = t & 63, fr = t >> 6;
        const int o0 = fr & 3, kc = fr >> 2;
        const int l15 = lane & 15, q4 = lane >> 4;
        short8 h8, l8;
        #pragma unroll
        for (int e = 0; e < 8; ++e) {
            const float v = NW[(kc * 32 + q4 * 8 + e) * O_ + o0 * 16 + l15];
            ushort hh, ll; bf16split(v, hh, ll);
            h8[e] = (short)hh; l8[e] = (short)ll;
        }
        *(short8*)&nwf[(size_t)(fr * 2) * 512 + lane * 8]     = h8;
        *(short8*)&nwf[(size_t)(fr * 2 + 1) * 512 + lane * 8] = l8;
    }
}

#define SP_STRIDE 520   // pad: q4 row offsets land on banks {0,8,16,24}

// ---------------------------------------------------------------------------
// attn_scores: block = (i-pair, b). Wave w owns o = w*16..+15 for BOTH i's.
// B-tiles staged via global_load_lds into 2x8KB dbuf, 1 barrier/tile.
// am partials combined via ds_add_f32 into padded sP. Aggregation via MFMA.
// ---------------------------------------------------------------------------
__global__ __launch_bounds__(256, 3) void attn_scores(
    const float* __restrict__ x,
    const ushort* __restrict__ xf,
    const ushort* __restrict__ xfT,
    const float* __restrict__ Wa,
    const float* __restrict__ ba,
    const float* __restrict__ AW,
    ushort* __restrict__ X1h, ushort* __restrict__ X1l)
{
    __shared__ ushort sB[2][8][512];          // 16KB dbuf; reused as sXp f32[2][16][128]
    __shared__ float  sP[8 * SP_STRIDE];      // [i*4+h][j] logits -> probs (16.6KB)

    const int tid  = threadIdx.x;
    const int ip   = blockIdx.x;
    const int bB   = blockIdx.y;
    const int lane = tid & 63;
    const int w    = tid >> 6;
    const int l15  = lane & 15;
    const int q4   = lane >> 4;
    const int i0   = ip * 2;
    const f32x4 z = {0.f, 0.f, 0.f, 0.f};

    // ---- stage tile 0 (async DMA) as early as possible ----
    const ushort* xfb = xf + (size_t)(bB * 32) * 8 * 512;
    gload_lds16(xfb + (size_t)(2 * w) * 512 + lane * 8,     &sB[0][2 * w][0]);
    gload_lds16(xfb + (size_t)(2 * w + 1) * 512 + lane * 8, &sB[0][2 * w + 1][0]);

    // ---- zero logit accumulator ----
    for (int k = tid; k < 8 * SP_STRIDE; k += 256) sP[k] = 0.f;

    // ---- A-frags: G^T rows o = w*16+l15 for both i's, built in regs ----
    const float* xi0 = x + ((size_t)bB * N_ + i0) * D_;
    const float* xi1 = xi0 + D_;
    const int oa = w * 16 + l15;
    short8 gh0[4], gl0[4], gh1[4], gl1[4];
    #pragma unroll
    for (int kc = 0; kc < 4; ++kc) {
        const int d0 = kc * 32 + q4 * 8;
        const f32x4 a0 = *(const f32x4*)&xi0[d0];
        const f32x4 a1 = *(const f32x4*)&xi0[d0 + 4];
        const f32x4 c0 = *(const f32x4*)&xi1[d0];
        const f32x4 c1 = *(const f32x4*)&xi1[d0 + 4];
        #pragma unroll
        for (int e = 0; e < 8; ++e) {
            const float wv  = Wa[(d0 + e) * O_ + oa];
            const float xe0 = (e < 4) ? a0[e & 3] : a1[e & 3];
            const float xe1 = (e < 4) ? c0[e & 3] : c1[e & 3];
            ushort h, l;
            bf16split(xe0 * wv, h, l); gh0[kc][e] = (short)h; gl0[kc][e] = (short)l;
            bf16split(xe1 * wv, h, l); gh1[kc][e] = (short)h; gl1[kc][e] = (short)l;
        }
    }

    // ---- epilogue constants (o-dependent only, shared by both i's) ----
    const int oc = w * 16 + q4 * 4;
    const f32x4 aw0 = *(const f32x4*)&AW[(oc + 0) * H_];
    const f32x4 aw1 = *(const f32x4*)&AW[(oc + 1) * H_];
    const f32x4 aw2 = *(const f32x4*)&AW[(oc + 2) * H_];
    const f32x4 aw3 = *(const f32x4*)&AW[(oc + 3) * H_];
    const f32x4 b2 = { 2.f * ba[oc], 2.f * ba[oc + 1], 2.f * ba[oc + 2], 2.f * ba[oc + 3] };

    asm volatile("s_waitcnt vmcnt(0)" ::: "memory");
    __syncthreads();   // tile 0 resident, sP zeroed

    // ---- phase 1: 32 tiles, DMA-dbuf, 1 barrier/tile ----
    for (int jf = 0; jf < 32; ++jf) {
        const int buf = jf & 1;
        if (jf < 31) {
            const int nb = buf ^ 1;
            const ushort* src = xfb + (size_t)(jf + 1) * 8 * 512;
            gload_lds16(src + (size_t)(2 * w) * 512 + lane * 8,     &sB[nb][2 * w][0]);
            gload_lds16(src + (size_t)(2 * w + 1) * 512 + lane * 8, &sB[nb][2 * w + 1][0]);
        }

        f32x4 acc0 = z, acc1 = z;
        #pragma unroll
        for (int kc = 0; kc < 4; ++kc) {
            const short8 bh = *(const short8*)&sB[buf][2 * kc][lane * 8];
            const short8 bl = *(const short8*)&sB[buf][2 * kc + 1][lane * 8];
            acc0 = __builtin_amdgcn_mfma_f32_16x16x32_bf16(gh0[kc], bh, acc0, 0, 0, 0);
            acc0 = __builtin_amdgcn_mfma_f32_16x16x32_bf16(gl0[kc], bh, acc0, 0, 0, 0);
            acc0 = __builtin_amdgcn_mfma_f32_16x16x32_bf16(gh0[kc], bl, acc0, 0, 0, 0);
            acc1 = __builtin_amdgcn_mfma_f32_16x16x32_bf16(gh1[kc], bh, acc1, 0, 0, 0);
            acc1 = __builtin_amdgcn_mfma_f32_16x16x32_bf16(gl1[kc], bh, acc1, 0, 0, 0);
            acc1 = __builtin_amdgcn_mfma_f32_16x16x32_bf16(gh1[kc], bl, acc1, 0, 0, 0);
        }

        // epilogue per i: tanh + am, reduce over wave's 16 o's, ds_add combine
        #pragma unroll
        for (int ii = 0; ii < 2; ++ii) {
            const f32x4 acc = ii ? acc1 : acc0;
            f32x4 am;
            const float e0 = __expf(fmaf(acc[0], 2.f, b2[0]));
            am  = fmaf(-2.f, __builtin_amdgcn_rcpf(e0 + 1.f), 1.f) * aw0;
            const float e1 = __expf(fmaf(acc[1], 2.f, b2[1]));
            am += fmaf(-2.f, __builtin_amdgcn_rcpf(e1 + 1.f), 1.f) * aw1;
            const float e2 = __expf(fmaf(acc[2], 2.f, b2[2]));
            am += fmaf(-2.f, __builtin_amdgcn_rcpf(e2 + 1.f), 1.f) * aw2;
            const float e3 = __expf(fmaf(acc[3], 2.f, b2[3]));
            am += fmaf(-2.f, __builtin_amdgcn_rcpf(e3 + 1.f), 1.f) * aw3;
            #pragma unroll
            for (int k = 0; k < 4; ++k) {
                am[k] += __shfl_xor(am[k], 16);
                am[k] += __shfl_xor(am[k], 32);
            }
            const float amsel = (q4 == 0) ? am[0] : (q4 == 1) ? am[1] : (q4 == 2) ? am[2] : am[3];
            atomicAdd(&sP[(ii * 4 + q4) * SP_STRIDE + jf * 16 + l15], amsel);
        }

        asm volatile("s_waitcnt vmcnt(0)" ::: "memory");   // next tile's DMA done
        __syncthreads();                                    // all reads of buf done
    }

    // ---- phase 2: softmax over j; 8 (i,h) rows over 4 waves ----
    #pragma unroll
    for (int rr = 0; rr < 2; ++rr) {
        const int r = w * 2 + rr;               // r = i*4+h
        float* row = &sP[r * SP_STRIDE];
        float v[8];
        float m = -INFINITY;
        #pragma unroll
        for (int k = 0; k < 8; ++k) {
            v[k] = row[k * 64 + lane];
            m = fmaxf(m, v[k]);
        }
        #pragma unroll
        for (int s = 32; s >= 1; s >>= 1) m = fmaxf(m, __shfl_xor(m, s));
        float l = 0.f;
        #pragma unroll
        for (int k = 0; k < 8; ++k) { v[k] = __expf(v[k] - m); l += v[k]; }
        #pragma unroll
        for (int s = 32; s >= 1; s >>= 1) l += __shfl_xor(l, s);
        const float rinv = 1.f / l;
        #pragma unroll
        for (int k = 0; k < 8; ++k) row[k * 64 + lane] = v[k] * rinv;
    }
    __syncthreads();

    // ---- phase 3: x1 = P.X via MFMA; xfT loads shared across both i's ----
    float* sXp = (float*)sB;   // [2 i][16 rows][128 d]
    #pragma unroll
    for (int pass = 0; pass < 2; ++pass) {
        f32x4 aA[4], aB[4];
        #pragma unroll
        for (int k = 0; k < 4; ++k) { aA[k] = z; aB[k] = z; }
        #pragma unroll
        for (int c = 0; c < 4; ++c) {
            const int kc = w * 4 + c;
            short8 pah0, pal0, pah1, pal1;
            #pragma unroll
            for (int ii = 0; ii < 2; ++ii) {
                const int base = (ii * 4 + (l15 & 3)) * SP_STRIDE + kc * 32 + q4 * 8;
                const f32x4 p0 = *(const f32x4*)&sP[base];
                const f32x4 p1 = *(const f32x4*)&sP[base + 4];
                float pv[8] = {p0[0], p0[1], p0[2], p0[3], p1[0], p1[1], p1[2], p1[3]};
                short8 ph, pl;
                #pragma unroll
                for (int e = 0; e < 8; ++e) {
                    ushort h, l; bf16split(pv[e], h, l);
                    ph[e] = (short)h; pl[e] = (short)l;
                }
                if (ii == 0) { pah0 = ph; pal0 = pl; } else { pah1 = ph; pal1 = pl; }
            }
            #pragma unroll
            for (int n4 = 0; n4 < 4; ++n4) {
                const int nf = pass * 4 + n4;
                const size_t f2 = ((size_t)(bB * 16 + kc) * 8 + nf) * 2;
                const short8 xh = *(const short8*)&xfT[f2 * 512 + lane * 8];
                const short8 xl = *(const short8*)&xfT[(f2 + 1) * 512 + lane * 8];
                aA[n4] = __builtin_amdgcn_mfma_f32_16x16x32_bf16(pah0, xh, aA[n4], 0, 0, 0);
                aA[n4] = __builtin_amdgcn_mfma_f32_16x16x32_bf16(pal0, xh, aA[n4], 0, 0, 0);
                aA[n4] = __builtin_amdgcn_mfma_f32_16x16x32_bf16(pah0, xl, aA[n4], 0, 0, 0);
                aB[n4] = __builtin_amdgcn_mfma_f32_16x16x32_bf16(pah1, xh, aB[n4], 0, 0, 0);
                aB[n4] = __builtin_amdgcn_mfma_f32_16x16x32_bf16(pal1, xh, aB[n4], 0, 0, 0);
                aB[n4] = __builtin_amdgcn_mfma_f32_16x16x32_bf16(pah1, xl, aB[n4], 0, 0, 0);
            }
        }
        if (q4 == 0) {
            #pragma unroll
            for (int n4 = 0; n4 < 4; ++n4) {
                #pragma unroll
                for (int r = 0; r < 4; ++r) {
                    sXp[0 * 2048 + (w * 4 + r) * 128 + (pass * 4 + n4) * 16 + l15] = aA[n4][r];
                    sXp[1 * 2048 + (w * 4 + r) * 128 + (pass * 4 + n4) * 16 + l15] = aB[n4][r];
                }
            }
        }
    }
    __syncthreads();

    // ---- phase 3b: reduce wave partials, split, store X1 for both i's ----
    #pragma unroll
    for (int ii = 0; ii < 2; ++ii) {
        const int kap = tid * 2;
        const size_t row = (size_t)bB * N_ + i0 + ii;
        float v0 = 0.f, v1 = 0.f;
        #pragma unroll
        for (int ww = 0; ww < 4; ++ww) {
            v0 += sXp[ii * 2048 + (ww * 4 + (kap >> 7)) * 128 + (kap & 127)];
            v1 += sXp[ii * 2048 + (ww * 4 + ((kap + 1) >> 7)) * 128 + ((kap + 1) & 127)];
        }
        ushort h0, l0, h1, l1;
        bf16split(v0, h0, l0);
        bf16split(v1, h1, l1);
        *(uint*)&X1h[row * 512 + kap] = (uint)h0 | ((uint)h1 << 16);
        *(uint*)&X1l[row * 512 + kap] = (uint)l0 | ((uint)l1 << 16);
    }
}

// ---------------------------------------------------------------------------
// proj_y_part: y = x1.PW' + x.NW + biases (MFMA) + per-block BN partial sums.
// ---------------------------------------------------------------------------
__global__ __launch_bounds__(256) void proj_y_part(
    const ushort* __restrict__ X1h, const ushort* __restrict__ X1l,
    const ushort* __restrict__ xf,
    const ushort* __restrict__ pwf, const ushort* __restrict__ nwf,
    const float* __restrict__ PWb, const float* __restrict__ NWb,
    float* __restrict__ y, float* __restrict__ part)
{
    const int tid = threadIdx.x, bid = blockIdx.x;
    const int lane = tid & 63, w = tid >> 6;
    const int l15 = lane & 15, q4 = lane >> 4;
    const int bi0 = bid * 16;
    const int b = bi0 >> 9, ig = (bi0 >> 4) & 31;

    f32x4 acc = {0.f, 0.f, 0.f, 0.f};
    #pragma unroll
    for (int kc = 0; kc < 16; ++kc) {
        const size_t arow = (size_t)(bi0 + l15) * 512 + kc * 32 + q4 * 8;
        const short8 ah = *(const short8*)&X1h[arow];
        const short8 al = *(const short8*)&X1l[arow];
        const int f3 = (kc * 4 + w) * 2;
        const short8 bhv = *(const short8*)&pwf[(size_t)f3 * 512 + lane * 8];
        const short8 blv = *(const short8*)&pwf[(size_t)(f3 + 1) * 512 + lane * 8];
        acc = __builtin_amdgcn_mfma_f32_16x16x32_bf16(ah, bhv, acc, 0, 0, 0);
        acc = __builtin_amdgcn_mfma_f32_16x16x32_bf16(al, bhv, acc, 0, 0, 0);
        acc = __builtin_amdgcn_mfma_f32_16x16x32_bf16(ah, blv, acc, 0, 0, 0);
    }
    #pragma unroll
    for (int kc = 0; kc < 4; ++kc) {
        const size_t fi = ((size_t)(b * 32 + ig) * 4 + kc) * 2;
        const short8 ah = *(const short8*)&xf[fi * 512 + lane * 8];
        const short8 al = *(const short8*)&xf[(fi + 1) * 512 + lane * 8];
        const int f4 = (kc * 4 + w) * 2;
        const short8 bhv = *(const short8*)&nwf[(size_t)f4 * 512 + lane * 8];
        const short8 blv = *(const short8*)&nwf[(size_t)(f4 + 1) * 512 + lane * 8];
        acc = __builtin_amdgcn_mfma_f32_16x16x32_bf16(ah, bhv, acc, 0, 0, 0);
        acc = __builtin_amdgcn_mfma_f32_16x16x32_bf16(al, bhv, acc, 0, 0, 0);
        acc = __builtin_amdgcn_mfma_f32_16x16x32_bf16(ah, blv, acc, 0, 0, 0);
    }
    const int oo = w * 16 + l15;
    const float bias = PWb[oo] + NWb[oo];
    float s = 0.f, sq = 0.f;
    #pragma unroll
    for (int r = 0; r < 4; ++r) {
        const float yv = acc[r] + bias;
        y[(size_t)(bi0 + q4 * 4 + r) * O_ + oo] = yv;
        s += yv; sq += yv * yv;
    }
    s  += __shfl_xor(s, 16);  s  += __shfl_xor(s, 32);
    sq += __shfl_xor(sq, 16); sq += __shfl_xor(sq, 32);
    if (q4 == 0) {
        part[bid * 256 + oo]       = s;
        part[bid * 256 + 128 + oo] = sq;
    }
}

__global__ __launch_bounds__(256) void bn_final(
    const float* __restrict__ part, const float* __restrict__ gamma,
    const float* __restrict__ beta, float* __restrict__ stats)
{
    const int tid = threadIdx.x, o = tid & 63, g = tid >> 6;
    float s = 0.f, sq = 0.f;
    #pragma unroll 4
    for (int k = 0; k < 32; ++k) {
        const int blk = g * 32 + k;
        s  += part[blk * 256 + o];
        sq += part[blk * 256 + 128 + o];
    }
    __shared__ float ls[4][64], lq[4][64];
    ls[g][o] = s; lq[g][o] = sq;
    __syncthreads();
    if (tid < 64) {
        const float inv = 1.f / 2048.f;
        const float ts = ls[0][tid] + ls[1][tid] + ls[2][tid] + ls[3][tid];
        const float tq = lq[0][tid] + lq[1][tid] + lq[2][tid] + lq[3][tid];
        const float mu  = ts * inv;
        const float var = tq * inv - mu * mu;
        const float rstd = rsqrtf(var + 1e-5f);
        const float sc = gamma[tid] * rstd;
        stats[tid]      = sc;
        stats[64 + tid] = beta[tid] - mu * sc;
    }
}

__global__ __launch_bounds__(256) void bn_apply(
    float* __restrict__ y, const float* __restrict__ stats)
{
    const int idx = blockIdx.x * 256 + threadIdx.x;
    f32x4 v = *(f32x4*)&y[idx * 4];
    const int o0 = (idx * 4) & 63;
    #pragma unroll
    for (int k = 0; k < 4; ++k) {
        const float t = v[k] * stats[o0 + k] + stats[64 + o0 + k];
        v[k] = t > 0.f ? SELU_SCALE * t : SELU_SCALE_ALPHA * (__expf(t) - 1.f);
    }
    *(f32x4*)&y[idx * 4] = v;
}

extern "C" void kernel_launch(void* const* d_in, const int* in_sizes, int n_in,
                              void* d_out, int out_size, void* d_ws, size_t ws_size,
                              hipStream_t stream)
{
    (void)in_sizes; (void)n_in; (void)out_size; (void)ws_size;
    const float* x     = (const float*)d_in[0];
    const float* Wa    = (const float*)d_in[1];
    const float* ba    = (const float*)d_in[2];
    const float* AW    = (const float*)d_in[3];
    const float* PW    = (const float*)d_in[4];
    const float* PWb   = (const float*)d_in[5];
    const float* NW    = (const float*)d_in[6];
    const float* NWb   = (const float*)d_in[7];
    const float* gamma = (const float*)d_in[8];
    const float* beta  = (const float*)d_in[9];

    char* ws = (char*)d_ws;
    ushort* xf    = (ushort*)ws;                                   // 1 MB
    ushort* xfT   = (ushort*)(ws + (1 << 20));                     // 1 MB
    ushort* X1h   = (ushort*)(ws + (2 << 20));                     // 2 MB
    ushort* X1l   = (ushort*)(ws + (4 << 20));                     // 2 MB
    ushort* pwf   = (ushort*)(ws + (6 << 20));                     // 128 KB
    ushort* nwf   = (ushort*)(ws + (6 << 20) + (128 << 10));       // 32 KB
    float*  part  = (float*)(ws + (6 << 20) + (160 << 10));        // 128 KB
    float*  stats = (float*)(ws + (6 << 20) + (288 << 10));        // 512 B
    float*  y     = (float*)d_out;

    prep_frags<<<276, 256, 0, stream>>>(x, PW, NW, xf, xfT, pwf, nwf);
    attn_scores<<<dim3(N_ / 2, B_), 256, 0, stream>>>(x, xf, xfT, Wa, ba, AW, X1h, X1l);
    proj_y_part<<<128, 256, 0, stream>>>(X1h, X1l, xf, pwf, nwf, PWb, NWb, y, part);
    bn_final<<<1, 256, 0, stream>>>(part, gamma, beta, stats);
    bn_apply<<<128, 256, 0, stream>>>(y, stats);
}